// Round 8
// baseline (260.047 us; speedup 1.0000x reference)
//
#include <hip/hip_runtime.h>
#include <hip/hip_bf16.h>

typedef __bf16 bf16_t;
typedef __bf16 bf16x4 __attribute__((ext_vector_type(4)));
typedef __bf16 bf16x8 __attribute__((ext_vector_type(8)));
typedef float f32x16 __attribute__((ext_vector_type(16)));

#define E_DIM 1024
#define SEQ   2048
#define NBATCH 4

#define BARR()  asm volatile("s_barrier" ::: "memory")
#define VMC12() asm volatile("s_waitcnt vmcnt(12)" ::: "memory")
#define VMC0()  asm volatile("s_waitcnt vmcnt(0)" ::: "memory")

// ---------------- all casts in one dispatch (row-major bf16) ----------------
__global__ __launch_bounds__(256) void k_cast_all(
    const float* __restrict__ q, const float* __restrict__ k, const float* __restrict__ v,
    const float* __restrict__ wq, const float* __restrict__ wk,
    const float* __restrict__ wv, const float* __restrict__ wo,
    bf16_t* __restrict__ xq, bf16_t* __restrict__ xk, bf16_t* __restrict__ xv,
    bf16_t* __restrict__ wqb, bf16_t* __restrict__ wkb,
    bf16_t* __restrict__ wvb, bf16_t* __restrict__ wob) {
  const int b = blockIdx.x;
  const float* s; bf16_t* d; long base;
  if (b < 4096)        { s = q; d = xq; base = (long)b * 2048; }
  else if (b < 8192)   { s = k; d = xk; base = (long)(b - 4096) * 2048; }
  else if (b < 12288)  { s = v; d = xv; base = (long)(b - 8192) * 2048; }
  else {
    const int w = (b - 12288) >> 9, r = (b - 12288) & 511;
    s = (w == 0) ? wq : (w == 1) ? wk : (w == 2) ? wv : wo;
    d = (w == 0) ? wqb : (w == 1) ? wkb : (w == 2) ? wvb : wob;
    base = (long)r * 2048;
  }
  const long i = base + threadIdx.x * 8;
  const float4 a = *(const float4*)(s + i);
  const float4 c = *(const float4*)(s + i + 4);
  bf16x8 o;
  o[0] = (bf16_t)a.x; o[1] = (bf16_t)a.y; o[2] = (bf16_t)a.z; o[3] = (bf16_t)a.w;
  o[4] = (bf16_t)c.x; o[5] = (bf16_t)c.y; o[6] = (bf16_t)c.z; o[7] = (bf16_t)c.w;
  *(bf16x8*)(d + i) = o;
}

// =================================================================================
// Triple-buffer counted-vmcnt GEMM.  C = scale*(A @ B^T) + bias (+residual/exp/rs).
// A:[M][K] bf16 (lda), B:[N][K] bf16 (ldb), K-contiguous.
// Tile 128x256, BK=64, 512 thr = 8 waves (2M x 4N), per-wave 64x64 via
// mfma_f32_32x32x16_bf16 (2x2 frags, r7-verified body/epilogue).
// LDS: 3 buffers x (A 16KB + B 32KB) = 144KB.  Iter T:
//   BARR (tile T-1's readers done -> buf (T+2)%3 free)
//   stage tile T+2 -> buf (T+2)%3   (6 x global_load_lds, 8KB units)
//   vmcnt(12)  == retire exactly tile T's 6 loads; T+1,T+2 (12) stay in flight
//                -> prefetch cover ~= 2 K-tile periods >> HBM latency
//   BARR (all waves' tile-T loads visible)
//   compute tile T: 16 ds_read_b128 + 16 MFMA (+8 ones-MFMA), compiler-scheduled
// T2 XOR-swizzle: linear GLL dest + inverse-swizzled source + swizzled ds_read.
// OUTMODE 0: f32+bias+residual, 1: bf16+bias, 2: bf16 transposed Vt[b][col][s],
// 3: bf16 exp(v*scale).  RS: ones-MFMA row sums, scale rows by 1/rs (PV).
// =================================================================================
template <int OUTMODE, bool RS>
__global__ __launch_bounds__(512, 2) void k_g8(
    const bf16_t* __restrict__ A, int lda, long sA,
    const bf16_t* __restrict__ B, int ldb, long sB,
    void* __restrict__ Cv, int ldc, long sC,
    int K, float scale, const float* __restrict__ bias,
    const float* __restrict__ residual, int GM, int GN) {
  extern __shared__ char smem[];

  const int tid  = threadIdx.x;
  const int lane = tid & 63;
  const int wid  = tid >> 6;
  const int wm   = wid >> 2;     // 0..1  (M groups of 64)
  const int wn   = wid & 3;      // 0..3  (N groups of 64)
  const int hi   = lane >> 5;
  const int l31  = lane & 31;

  // T1: XCD swizzle (grids are multiples of 8)
  const int nwg  = gridDim.x;
  const int orig = blockIdx.x;
  const int wg   = (orig & 7) * (nwg >> 3) + (orig >> 3);
  const int zz   = wg / (GM * GN);
  const int rm   = wg - zz * (GM * GN);
  const int bm   = rm / GN;
  const int bn   = rm - bm * GN;
  const int brow = bm * 128;
  const int bcol = bn * 256;

#define GLL(gaddr, ldsoff)                                                       \
  __builtin_amdgcn_global_load_lds(                                             \
      (const __attribute__((address_space(1))) void*)(gaddr),                   \
      (__attribute__((address_space(3))) void*)(smem + (ldsoff)), 16, 0, 0)

  // staging sources: thread t covers row (t>>3) of each 64-row unit, 16B at
  // (t&7)*16; source col inverse-XOR-swizzled (rule 21), LDS dest linear.
  const int colk = ((tid & 7) ^ ((tid >> 3) & 7)) << 3;
  const bf16_t* Asrc = A + zz * sA + (long)(brow + (tid >> 3)) * lda + colk;
  const bf16_t* Bsrc = B + zz * sB + (long)(bcol + (tid >> 3)) * ldb + colk;
  const int ldsw = wid << 10;  // 8 waves x 1KB = one 8KB unit per GLL call

  const int NT = K >> 6;

  auto stage = [&](int t, int buf) {
    const long koff = (long)t * 64;
    const int bb = buf * 49152;
#pragma unroll
    for (int s = 0; s < 2; ++s)   // A: 128 rows = 2 units
      GLL(Asrc + (long)(s * 64) * lda + koff, bb + s * 8192 + ldsw);
#pragma unroll
    for (int s = 0; s < 4; ++s)   // B: 256 rows = 4 units
      GLL(Bsrc + (long)(s * 64) * ldb + koff, bb + 16384 + s * 8192 + ldsw);
  };

  f32x16 acc00 = {}, acc01 = {}, acc10 = {}, acc11 = {};
  f32x16 rs0 = {}, rs1 = {};
  bf16x8 vones;
#pragma unroll
  for (int i = 0; i < 8; ++i) vones[i] = (bf16_t)1.0f;

  const int ra = wm * 64 + l31;
  const int rb = wn * 64 + l31;
  const int swzA = (ra & 7) << 4;   // (ra+32)&7 == ra&7
  const int swzB = (rb & 7) << 4;

  // prologue: tiles 0,1 in flight (12 loads)
  stage(0, 0);
  stage(1 < NT ? 1 : 0, 1);

  for (int T = 0; T < NT; ++T) {
    BARR();  // tile T-1's readers done -> buf (T+2)%3 is free to overwrite
    stage(T + 2 < NT ? T + 2 : NT - 1, (T + 2) % 3);
    VMC12();  // tile T's 6 loads retired (oldest); 12 newer stay in flight
    BARR();   // all waves' tile-T data visible in LDS
    const char* bufp = smem + (T % 3) * 49152;
#pragma unroll
    for (int kk = 0; kk < 4; ++kk) {
      const int cb = kk * 32 + (hi << 4);
      bf16x8 a0 = *(const bf16x8*)(bufp + ra * 128 + (cb ^ swzA));
      bf16x8 a1 = *(const bf16x8*)(bufp + (ra + 32) * 128 + (cb ^ swzA));
      bf16x8 b0 = *(const bf16x8*)(bufp + 16384 + rb * 128 + (cb ^ swzB));
      bf16x8 b1 = *(const bf16x8*)(bufp + 16384 + (rb + 32) * 128 + (cb ^ swzB));
      acc00 = __builtin_amdgcn_mfma_f32_32x32x16_bf16(a0, b0, acc00, 0, 0, 0);
      acc01 = __builtin_amdgcn_mfma_f32_32x32x16_bf16(a0, b1, acc01, 0, 0, 0);
      acc10 = __builtin_amdgcn_mfma_f32_32x32x16_bf16(a1, b0, acc10, 0, 0, 0);
      acc11 = __builtin_amdgcn_mfma_f32_32x32x16_bf16(a1, b1, acc11, 0, 0, 0);
      if constexpr (RS) {
        rs0 = __builtin_amdgcn_mfma_f32_32x32x16_bf16(a0, vones, rs0, 0, 0, 0);
        rs1 = __builtin_amdgcn_mfma_f32_32x32x16_bf16(a1, vones, rs1, 0, 0, 0);
      }
    }
  }
  VMC0();

  // Epilogue (r7-verified). 32x32 C/D: col = lane&31, row = (reg&3)+8*(reg>>2)+4*hi
  float inv0[16], inv1[16];
  if constexpr (RS) {
#pragma unroll
    for (int i = 0; i < 16; ++i) { inv0[i] = 1.0f / rs0[i]; inv1[i] = 1.0f / rs1[i]; }
  }
  const int colb = bcol + wn * 64 + l31;
  const int rowb = brow + wm * 64 + (hi << 2);
#pragma unroll
  for (int mf = 0; mf < 2; ++mf) {
#pragma unroll
    for (int nf = 0; nf < 2; ++nf) {
      const f32x16 av = (mf == 0) ? (nf == 0 ? acc00 : acc01) : (nf == 0 ? acc10 : acc11);
      const int colg = colb + nf * 32;
      float bval = 0.0f;
      if constexpr (OUTMODE != 3) bval = bias ? bias[colg] : 0.0f;
#pragma unroll
      for (int g = 0; g < 4; ++g) {
        const int r0 = rowb + mf * 32 + g * 8;
        if constexpr (OUTMODE == 2) {
          bf16x4 pk;
#pragma unroll
          for (int j = 0; j < 4; ++j) pk[j] = (bf16_t)(av[g * 4 + j] * scale + bval);
          const long bb2 = (long)(r0 >> 11);
          const int ss = r0 & (SEQ - 1);
          *(bf16x4*)((bf16_t*)Cv + bb2 * ((long)E_DIM * SEQ) + (long)colg * SEQ + ss) = pk;
        } else {
#pragma unroll
          for (int j = 0; j < 4; ++j) {
            const int r = r0 + j;
            float v;
            if constexpr (OUTMODE == 3) v = __expf(av[g * 4 + j] * scale);
            else v = av[g * 4 + j] * scale + bval;
            if constexpr (RS) v *= (mf == 0 ? inv0[g * 4 + j] : inv1[g * 4 + j]);
            if (OUTMODE == 0 && residual) v += residual[(long)r * ldc + colg];
            const long idx = (long)zz * sC + (long)r * ldc + colg;
            if constexpr (OUTMODE == 0) ((float*)Cv)[idx] = v;
            else ((bf16_t*)Cv)[idx] = (bf16_t)v;
          }
        }
      }
    }
  }
#undef GLL
}

// ---------------- layernorm in-place on rows of 1024 f32 ----------------
__global__ __launch_bounds__(256) void k_layernorm(float* __restrict__ out,
                                                   const float* __restrict__ gamma,
                                                   const float* __restrict__ beta) {
  const long row = blockIdx.x;
  float* rp = out + row * 1024;
  const int t = threadIdx.x;
  const float4 v = *(const float4*)(rp + t * 4);
  float s = v.x + v.y + v.z + v.w;
#pragma unroll
  for (int o = 32; o; o >>= 1) s += __shfl_xor(s, o);
  __shared__ float red1[4], red2[4];
  const int lane = t & 63, w = t >> 6;
  if (lane == 0) red1[w] = s;
  __syncthreads();
  const float mu = (red1[0] + red1[1] + red1[2] + red1[3]) * (1.0f / 1024.0f);
  const float d0 = v.x - mu, d1 = v.y - mu, d2 = v.z - mu, d3 = v.w - mu;
  float ss = d0 * d0 + d1 * d1 + d2 * d2 + d3 * d3;
#pragma unroll
  for (int o = 32; o; o >>= 1) ss += __shfl_xor(ss, o);
  if (lane == 0) red2[w] = ss;
  __syncthreads();
  const float var = (red2[0] + red2[1] + red2[2] + red2[3]) * (1.0f / 1024.0f);
  const float rsq = rsqrtf(var + 1e-6f);
  const float4 g = *(const float4*)(gamma + t * 4);
  const float4 b = *(const float4*)(beta + t * 4);
  float4 o;
  o.x = d0 * rsq * g.x + b.x;
  o.y = d1 * rsq * g.y + b.y;
  o.z = d2 * rsq * g.z + b.z;
  o.w = d3 * rsq * g.w + b.w;
  *(float4*)(rp + t * 4) = o;
}

extern "C" void kernel_launch(void* const* d_in, const int* in_sizes, int n_in,
                              void* d_out, int out_size, void* d_ws, size_t ws_size,
                              hipStream_t stream) {
  const float* query = (const float*)d_in[0];
  const float* key   = (const float*)d_in[1];
  const float* value = (const float*)d_in[2];
  const float* Wq = (const float*)d_in[3];
  const float* bq = (const float*)d_in[4];
  const float* Wk = (const float*)d_in[5];
  const float* bk = (const float*)d_in[6];
  const float* Wv = (const float*)d_in[7];
  const float* bv = (const float*)d_in[8];
  const float* Wo = (const float*)d_in[9];
  const float* bo = (const float*)d_in[10];
  const float* gamma = (const float*)d_in[11];
  const float* beta  = (const float*)d_in[12];
  float* out = (float*)d_out;

  char* ws = (char*)d_ws;
  const size_t XSZ = (size_t)NBATCH * SEQ * E_DIM * 2;  // 16 MiB
  const size_t WSZ = (size_t)E_DIM * E_DIM * 2;         // 2 MiB
  const size_t B2  = 3 * XSZ;                           // 48 MiB boundary

  bf16_t* Xq  = (bf16_t*)(ws + 0);
  bf16_t* Xk  = (bf16_t*)(ws + XSZ);
  bf16_t* Xv  = (bf16_t*)(ws + 2 * XSZ);
  bf16_t* SC  = (bf16_t*)(ws + 0);   // exp-scores overlay dead X buffers
  bf16_t* Wqb = (bf16_t*)(ws + B2);
  bf16_t* Wkb = (bf16_t*)(ws + B2 + WSZ);
  bf16_t* Wvb = (bf16_t*)(ws + B2 + 2 * WSZ);
  bf16_t* Wob = (bf16_t*)(ws + B2 + 3 * WSZ);
  bf16_t* Qb  = (bf16_t*)(ws + B2 + 4 * WSZ);
  bf16_t* Kb  = (bf16_t*)(ws + B2 + 4 * WSZ + XSZ);
  bf16_t* Vt  = (bf16_t*)(ws + B2 + 4 * WSZ + 2 * XSZ);
  bf16_t* Ctx = (bf16_t*)(ws + B2 + 4 * WSZ + 3 * XSZ);

  const int NTOK = NBATCH * SEQ;  // 8192
  const int SMB = 147456;         // 3 x 48KB

  hipFuncSetAttribute((const void*)k_g8<1, false>, hipFuncAttributeMaxDynamicSharedMemorySize, SMB);
  hipFuncSetAttribute((const void*)k_g8<2, false>, hipFuncAttributeMaxDynamicSharedMemorySize, SMB);
  hipFuncSetAttribute((const void*)k_g8<3, false>, hipFuncAttributeMaxDynamicSharedMemorySize, SMB);
  hipFuncSetAttribute((const void*)k_g8<1, true>,  hipFuncAttributeMaxDynamicSharedMemorySize, SMB);
  hipFuncSetAttribute((const void*)k_g8<0, false>, hipFuncAttributeMaxDynamicSharedMemorySize, SMB);

  // 1) casts
  k_cast_all<<<dim3(14336), 256, 0, stream>>>(query, key, value, Wq, Wk, Wv, Wo,
                                              Xq, Xk, Xv, Wqb, Wkb, Wvb, Wob);

  // 2) projections: grid 64x4 = 256 (full GPU, 1 block/CU)
  k_g8<1, false><<<256, 512, SMB, stream>>>(
      Xq, E_DIM, 0, Wqb, E_DIM, 0, Qb, E_DIM, 0, E_DIM, 1.0f, bq, nullptr, 64, 4);
  k_g8<1, false><<<256, 512, SMB, stream>>>(
      Xk, E_DIM, 0, Wkb, E_DIM, 0, Kb, E_DIM, 0, E_DIM, 1.0f, bk, nullptr, 64, 4);
  k_g8<2, false><<<256, 512, SMB, stream>>>(
      Xv, E_DIM, 0, Wvb, E_DIM, 0, Vt, 0, 0, E_DIM, 1.0f, bv, nullptr, 64, 4);

  // 3) P = exp(Q K^T / 32) -> bf16 (grid 16x8x4 = 512, two full rounds)
  k_g8<3, false><<<512, 512, SMB, stream>>>(
      Qb, E_DIM, (long)SEQ * E_DIM, Kb, E_DIM, (long)SEQ * E_DIM,
      SC, SEQ, (long)SEQ * SEQ, E_DIM, 0.03125f, nullptr, nullptr, 16, 8);

  // 4) ctx = (P @ V) / rowsum — ones-MFMA rowsum, lane-local normalize
  //    (grid 16x4x4 = 256)
  k_g8<1, true><<<256, 512, SMB, stream>>>(
      SC, SEQ, (long)SEQ * SEQ, Vt, SEQ, (long)E_DIM * SEQ,
      Ctx, E_DIM, (long)SEQ * E_DIM, SEQ, 1.0f, nullptr, nullptr, 16, 4);

  // 5) out = ctx Wo^T + bo + residual(query), f32 into d_out (grid 256)
  k_g8<0, false><<<256, 512, SMB, stream>>>(
      Ctx, E_DIM, 0, Wob, E_DIM, 0, out, E_DIM, 0, E_DIM, 1.0f, bo, query, 64, 4);

  // 6) layernorm in-place
  k_layernorm<<<dim3(NTOK), 256, 0, stream>>>(out, gamma, beta);
}

// Round 9
// 232.333 us; speedup vs baseline: 1.1193x; 1.1193x over previous
//
#include <hip/hip_runtime.h>
#include <hip/hip_bf16.h>

typedef __bf16 bf16_t;
typedef __bf16 bf16x4 __attribute__((ext_vector_type(4)));
typedef __bf16 bf16x8 __attribute__((ext_vector_type(8)));
typedef float f32x4 __attribute__((ext_vector_type(4)));

#define E_DIM 1024
#define SEQ   2048
#define NBATCH 4

#define BARR()  asm volatile("s_barrier" ::: "memory")
#define LGKM0() asm volatile("s_waitcnt lgkmcnt(0)" ::: "memory")
#define LGKM8() asm volatile("s_waitcnt lgkmcnt(8)" ::: "memory")
#define VMC6()  asm volatile("s_waitcnt vmcnt(6)" ::: "memory")
#define VMC4()  asm volatile("s_waitcnt vmcnt(4)" ::: "memory")
#define VMC0()  asm volatile("s_waitcnt vmcnt(0)" ::: "memory")

// ---------------- all casts in one dispatch (plain row-major bf16) -------------
__global__ __launch_bounds__(256) void k_cast_all(
    const float* __restrict__ q, const float* __restrict__ k, const float* __restrict__ v,
    const float* __restrict__ wq, const float* __restrict__ wk,
    const float* __restrict__ wv, const float* __restrict__ wo,
    bf16_t* __restrict__ xq, bf16_t* __restrict__ xk, bf16_t* __restrict__ xv,
    bf16_t* __restrict__ wqb, bf16_t* __restrict__ wkb,
    bf16_t* __restrict__ wvb, bf16_t* __restrict__ wob) {
  const int b = blockIdx.x;
  const float* s; bf16_t* d; long base;
  if (b < 4096)        { s = q; d = xq; base = (long)b * 2048; }
  else if (b < 8192)   { s = k; d = xk; base = (long)(b - 4096) * 2048; }
  else if (b < 12288)  { s = v; d = xv; base = (long)(b - 8192) * 2048; }
  else {
    const int w = (b - 12288) >> 9, r = (b - 12288) & 511;
    s = (w == 0) ? wq : (w == 1) ? wk : (w == 2) ? wv : wo;
    d = (w == 0) ? wqb : (w == 1) ? wkb : (w == 2) ? wvb : wob;
    base = (long)r * 2048;
  }
  const long i = base + threadIdx.x * 8;
  const float4 a = *(const float4*)(s + i);
  const float4 c = *(const float4*)(s + i + 4);
  bf16x8 o;
  o[0] = (bf16_t)a.x; o[1] = (bf16_t)a.y; o[2] = (bf16_t)a.z; o[3] = (bf16_t)a.w;
  o[4] = (bf16_t)c.x; o[5] = (bf16_t)c.y; o[6] = (bf16_t)c.z; o[7] = (bf16_t)c.w;
  *(bf16x8*)(d + i) = o;
}

// =================================================================================
// 4-phase deep-pipelined GEMM (round-6-verified), C = scale*(A @ B^T)+bias(...).
// A:[M][K] bf16 (lda), B:[N][K] bf16 (ldb), K-contiguous. 512 thr = 8 waves (2x4).
// MREP=8: BM=256 (per-wave 128x64); MREP=4: BM=128 (per-wave 64x64). BN=256.
// mfma_f32_16x16x32_bf16 (zero-bank-conflict fragment reads with XOR-8 swizzle).
// Double-buffered LDS; per tile: ph0{ldA0,ldB0; stage Bh1(t+1)->buf^1},
// ph1{ldB1}, ph2{ldA1; stage Bh0(t+2)->cur}, ph3{stage A(t+2)->cur; vmcnt(6|4)}.
// Counted vmcnt never drains in main loop (ledger verified rounds 6/8-pass).
// OUTMODE 0:f32+bias+residual, 1:bf16+bias, 2:bf16 transposed Vt[b][col][s]+bias,
// 3: bf16 exp(v*scale).  RS: ones-MFMA rowsum (lane-local), scale rows by 1/rs.
// QKV3: merged Q/K/V projection dispatch — grid 768 = 3 slabs of 256 wg; per-slab
// pointer select; slab 2 (V) uses the transposed store.
// =================================================================================
template <int MREP, int OUTMODE, bool RS, bool QKV3 = false>
__global__ __launch_bounds__(512, 2) void k_g6(
    const bf16_t* __restrict__ A, int lda, long sA,
    const bf16_t* __restrict__ B, int ldb, long sB,
    void* __restrict__ Cv, int ldc, long sC,
    int K, float scale, const float* __restrict__ bias,
    const float* __restrict__ residual, int GM, int GN,
    const bf16_t* __restrict__ A1 = nullptr, const bf16_t* __restrict__ A2 = nullptr,
    const bf16_t* __restrict__ B1 = nullptr, const bf16_t* __restrict__ B2 = nullptr,
    const float* __restrict__ bias1 = nullptr, const float* __restrict__ bias2 = nullptr,
    void* __restrict__ Cv1 = nullptr, void* __restrict__ Cv2 = nullptr) {
  constexpr int WM  = MREP * 16;       // per-wave M rows
  constexpr int BM  = WM * 2;          // block M
  constexpr int ASZ = BM * 128;        // A tile bytes
  constexpr int BUFSZ = ASZ + 32768;   // A + B per buffer
  constexpr int MH  = MREP / 2;
  extern __shared__ char smem[];

  const int tid  = threadIdx.x;
  const int lane = tid & 63;
  const int wid  = tid >> 6;
  const int wm   = wid >> 2;           // 0..1
  const int wn   = wid & 3;            // 0..3
  const int l15  = lane & 15;
  const int lq   = lane >> 4;          // k-chunk 0..3

  // T1: XCD swizzle (grids are multiples of 8)
  const int nwg  = gridDim.x;
  const int orig = blockIdx.x;
  const int wg0  = (orig & 7) * (nwg >> 3) + (orig >> 3);

  int pid = 0, wg = wg0;
  if constexpr (QKV3) { pid = wg0 >> 8; wg = wg0 & 255; }

  const int zz   = wg / (GM * GN);
  const int rm   = wg - zz * (GM * GN);
  const int bm   = rm / GN;
  const int bn   = rm - bm * GN;
  const int brow = bm * BM;
  const int bcol = bn * 256;

  const bf16_t* Ap = A;
  const bf16_t* Bp = B;
  const float*  biasp = bias;
  void* Cvp = Cv;
  bool tr = (OUTMODE == 2);
  if constexpr (QKV3) {
    if (pid == 1) { Ap = A1; Bp = B1; biasp = bias1; Cvp = Cv1; }
    else if (pid == 2) { Ap = A2; Bp = B2; biasp = bias2; Cvp = Cv2; tr = true; }
  }

  // staging source (inverse-swizzled col; row&7 == (tid>>3)&7 since bases %64==0)
  const int colk = ((tid & 7) ^ ((tid >> 3) & 7)) << 3;
  const bf16_t* Asrc = Ap + zz * sA + (long)(brow + (tid >> 3)) * lda + colk;
  const bf16_t* Bsrc = Bp + zz * sB + (long)(bcol + (tid >> 3)) * ldb + colk;
  const int ldsw = wid << 10;
  const int NT = K >> 6;

#define GLL(gaddr, ldsoff)                                                       \
  __builtin_amdgcn_global_load_lds(                                             \
      (const __attribute__((address_space(1))) void*)(gaddr),                   \
      (__attribute__((address_space(3))) void*)(smem + (ldsoff)), 16, 0, 0)

  auto stA = [&](int tile, int buf, int half) {
#pragma unroll
    for (int s = 0; s < 2; ++s)
      GLL(Asrc + (long)(half * 128 + s * 64) * lda + tile * 64,
          buf * BUFSZ + half * 16384 + s * 8192 + ldsw);
  };
  auto stB = [&](int tile, int buf, int half) {
#pragma unroll
    for (int s = 0; s < 2; ++s)
      GLL(Bsrc + (long)(half * 128 + s * 64) * ldb + tile * 64,
          buf * BUFSZ + ASZ + half * 16384 + s * 8192 + ldsw);
  };

  f32x4 acc[MREP][4];
#pragma unroll
  for (int m = 0; m < MREP; ++m)
#pragma unroll
    for (int n = 0; n < 4; ++n) acc[m][n] = (f32x4){0.f, 0.f, 0.f, 0.f};
  f32x4 rs[MREP];
#pragma unroll
  for (int m = 0; m < MREP; ++m) rs[m] = (f32x4){0.f, 0.f, 0.f, 0.f};
  bf16x8 vones;
#pragma unroll
  for (int i = 0; i < 8; ++i) vones[i] = (bf16_t)1.0f;

  // ds_read fragment loaders (swizzled)
  auto ldA = [&](bf16x8 (&a)[MH][2], int cur, int mq) {
#pragma unroll
    for (int i = 0; i < MH; ++i) {
      const int row = wm * WM + (mq * MH + i) * 16 + l15;
#pragma unroll
      for (int kk = 0; kk < 2; ++kk) {
        const int byt = cur * BUFSZ + row * 128 + ((kk * 64 + lq * 16) ^ ((row & 7) << 4));
        a[i][kk] = *(const bf16x8*)(smem + byt);
      }
    }
  };
  auto ldB = [&](bf16x8 (&b)[2][2], int cur, int nq) {
#pragma unroll
    for (int n2 = 0; n2 < 2; ++n2) {
      const int row = wn * 64 + (nq * 2 + n2) * 16 + l15;
#pragma unroll
      for (int kk = 0; kk < 2; ++kk) {
        const int byt = cur * BUFSZ + ASZ + row * 128 + ((kk * 64 + lq * 16) ^ ((row & 7) << 4));
        b[n2][kk] = *(const bf16x8*)(smem + byt);
      }
    }
  };
  auto mmaq = [&](bf16x8 (&a)[MH][2], bf16x8 (&b)[2][2], int mq, int nq) {
    __builtin_amdgcn_s_setprio(1);
#pragma unroll
    for (int kk = 0; kk < 2; ++kk)
#pragma unroll
      for (int i = 0; i < MH; ++i)
#pragma unroll
        for (int n2 = 0; n2 < 2; ++n2)
          acc[mq * MH + i][nq * 2 + n2] = __builtin_amdgcn_mfma_f32_16x16x32_bf16(
              a[i][kk], b[n2][kk], acc[mq * MH + i][nq * 2 + n2], 0, 0, 0);
    __builtin_amdgcn_s_setprio(0);
  };
  auto mmars = [&](bf16x8 (&a)[MH][2], int mq) {
#pragma unroll
    for (int kk = 0; kk < 2; ++kk)
#pragma unroll
      for (int i = 0; i < MH; ++i)
        rs[mq * MH + i] = __builtin_amdgcn_mfma_f32_16x16x32_bf16(
            a[i][kk], vones, rs[mq * MH + i], 0, 0, 0);
  };

  // ---------------- prologue: t0 full + t1 {Bh0, A}; counted wait ---------------
  {
    const int t1c = 1 < NT ? 1 : 0;
    if constexpr (MREP == 8) {
      stB(0, 0, 0); stB(0, 0, 1); stA(0, 0, 0); stA(0, 0, 1);
      stB(t1c, 1, 0); stA(t1c, 1, 0); stA(t1c, 1, 1);
      VMC6();
    } else {
      stB(0, 0, 0); stB(0, 0, 1); stA(0, 0, 0);
      stB(t1c, 1, 0); stA(t1c, 1, 0);
      VMC4();
    }
    BARR();
  }

  bf16x8 a0[MH][2], a1[MH][2], b0[2][2], b1[2][2];
  auto tile = [&](int t, int cur) {
    const int t1 = t + 1 < NT ? t + 1 : NT - 1;
    const int t2 = t + 2 < NT ? t + 2 : NT - 1;
    // ph0: reads a0,b0 ; stage Bh1(t+1) -> other buffer (its readers done last tile)
    ldA(a0, cur, 0); ldB(b0, cur, 0);
    stB(t1, cur ^ 1, 1);
    if constexpr (MREP == 8) LGKM8();  // 12 ds_reads issued this phase (m201 detail)
    BARR(); LGKM0();
    mmaq(a0, b0, 0, 0);
    BARR();
    // ph1: reads b1
    ldB(b1, cur, 1);
    BARR(); LGKM0();
    mmaq(a0, b1, 0, 1);
    if constexpr (RS) mmars(a0, 0);
    BARR();
    // ph2: reads a1 ; stage Bh0(t+2) -> cur (B last read was ph1, barrier passed)
    ldA(a1, cur, 1);
    stB(t2, cur, 0);
    BARR(); LGKM0();
    mmaq(a1, b1, 1, 1);
    BARR();
    // ph3: stage A(t+2) -> cur (A last read ph2, barrier passed); counted vmcnt
    stA(t2, cur, 0);
    if constexpr (MREP == 8) stA(t2, cur, 1);
    BARR();
    mmaq(a1, b0, 1, 0);
    if constexpr (RS) mmars(a1, 1);
    if constexpr (MREP == 8) VMC6(); else VMC4();
    BARR();
  };

  for (int t = 0; t < NT; t += 2) {
    tile(t, 0);
    tile(t + 1, 1);
  }
  VMC0();

  // ---------------- epilogue (C/D 16x16: col=lane&15, row=(lane>>4)*4+j) --------
  const int colb = bcol + wn * 64 + l15;
  const int rowb = brow + wm * WM + lq * 4;
#pragma unroll
  for (int m = 0; m < MREP; ++m) {
    float inv[4];
    if constexpr (RS) {
#pragma unroll
      for (int j = 0; j < 4; ++j) inv[j] = 1.0f / rs[m][j];
    }
#pragma unroll
    for (int n = 0; n < 4; ++n) {
      const int colg = colb + n * 16;
      float bval = 0.0f;
      if constexpr (OUTMODE != 3) bval = biasp ? biasp[colg] : 0.0f;
      if ((OUTMODE == 2) || (QKV3 && tr)) {
        const int r0 = rowb + m * 16;
        bf16x4 pk;
#pragma unroll
        for (int j = 0; j < 4; ++j) pk[j] = (bf16_t)(acc[m][n][j] * scale + bval);
        const long bb = (long)(r0 >> 11);
        const int ss = r0 & (SEQ - 1);
        *(bf16x4*)((bf16_t*)Cvp + bb * ((long)E_DIM * SEQ) + (long)colg * SEQ + ss) = pk;
      } else {
#pragma unroll
        for (int j = 0; j < 4; ++j) {
          const int r = rowb + m * 16 + j;
          float v;
          if constexpr (OUTMODE == 3) v = __expf(acc[m][n][j] * scale);
          else v = acc[m][n][j] * scale + bval;
          if constexpr (RS) v *= inv[j];
          if (OUTMODE == 0 && residual) v += residual[(long)r * ldc + colg];
          const long idx = (long)zz * sC + (long)r * ldc + colg;
          if constexpr (OUTMODE == 0) ((float*)Cvp)[idx] = v;
          else ((bf16_t*)Cvp)[idx] = (bf16_t)v;
        }
      }
    }
  }
#undef GLL
}

// ---------------- layernorm in-place on rows of 1024 f32 ----------------
__global__ __launch_bounds__(256) void k_layernorm(float* __restrict__ out,
                                                   const float* __restrict__ gamma,
                                                   const float* __restrict__ beta) {
  const long row = blockIdx.x;
  float* rp = out + row * 1024;
  const int t = threadIdx.x;
  const float4 v = *(const float4*)(rp + t * 4);
  float s = v.x + v.y + v.z + v.w;
#pragma unroll
  for (int o = 32; o; o >>= 1) s += __shfl_xor(s, o);
  __shared__ float red1[4], red2[4];
  const int lane = t & 63, w = t >> 6;
  if (lane == 0) red1[w] = s;
  __syncthreads();
  const float mu = (red1[0] + red1[1] + red1[2] + red1[3]) * (1.0f / 1024.0f);
  const float d0 = v.x - mu, d1 = v.y - mu, d2 = v.z - mu, d3 = v.w - mu;
  float ss = d0 * d0 + d1 * d1 + d2 * d2 + d3 * d3;
#pragma unroll
  for (int o = 32; o; o >>= 1) ss += __shfl_xor(ss, o);
  if (lane == 0) red2[w] = ss;
  __syncthreads();
  const float var = (red2[0] + red2[1] + red2[2] + red2[3]) * (1.0f / 1024.0f);
  const float rsq = rsqrtf(var + 1e-6f);
  const float4 g = *(const float4*)(gamma + t * 4);
  const float4 b = *(const float4*)(beta + t * 4);
  float4 o;
  o.x = d0 * rsq * g.x + b.x;
  o.y = d1 * rsq * g.y + b.y;
  o.z = d2 * rsq * g.z + b.z;
  o.w = d3 * rsq * g.w + b.w;
  *(float4*)(rp + t * 4) = o;
}

extern "C" void kernel_launch(void* const* d_in, const int* in_sizes, int n_in,
                              void* d_out, int out_size, void* d_ws, size_t ws_size,
                              hipStream_t stream) {
  const float* query = (const float*)d_in[0];
  const float* key   = (const float*)d_in[1];
  const float* value = (const float*)d_in[2];
  const float* Wq = (const float*)d_in[3];
  const float* bq = (const float*)d_in[4];
  const float* Wk = (const float*)d_in[5];
  const float* bk = (const float*)d_in[6];
  const float* Wv = (const float*)d_in[7];
  const float* bv = (const float*)d_in[8];
  const float* Wo = (const float*)d_in[9];
  const float* bo = (const float*)d_in[10];
  const float* gamma = (const float*)d_in[11];
  const float* beta  = (const float*)d_in[12];
  float* out = (float*)d_out;

  char* ws = (char*)d_ws;
  const size_t XSZ = (size_t)NBATCH * SEQ * E_DIM * 2;  // 16 MiB
  const size_t WSZ = (size_t)E_DIM * E_DIM * 2;         // 2 MiB
  const size_t B2  = 3 * XSZ;                           // 48 MiB boundary

  bf16_t* Xq  = (bf16_t*)(ws + 0);
  bf16_t* Xk  = (bf16_t*)(ws + XSZ);
  bf16_t* Xv  = (bf16_t*)(ws + 2 * XSZ);
  bf16_t* SC  = (bf16_t*)(ws + 0);   // exp-scores overlay dead X buffers (33.5MB<48)
  bf16_t* Wqb = (bf16_t*)(ws + B2);
  bf16_t* Wkb = (bf16_t*)(ws + B2 + WSZ);
  bf16_t* Wvb = (bf16_t*)(ws + B2 + 2 * WSZ);
  bf16_t* Wob = (bf16_t*)(ws + B2 + 3 * WSZ);
  bf16_t* Qb  = (bf16_t*)(ws + B2 + 4 * WSZ);
  bf16_t* Kb  = (bf16_t*)(ws + B2 + 4 * WSZ + XSZ);
  bf16_t* Vt  = (bf16_t*)(ws + B2 + 4 * WSZ + 2 * XSZ);
  bf16_t* Ctx = (bf16_t*)(ws + B2 + 4 * WSZ + 3 * XSZ);

  const int NTOK = NBATCH * SEQ;  // 8192
  const int SM4 = 98304, SM8 = 131072;

  hipFuncSetAttribute((const void*)k_g6<4, 1, false, true>, hipFuncAttributeMaxDynamicSharedMemorySize, SM4);
  hipFuncSetAttribute((const void*)k_g6<4, 1, true>,  hipFuncAttributeMaxDynamicSharedMemorySize, SM4);
  hipFuncSetAttribute((const void*)k_g6<4, 0, false>, hipFuncAttributeMaxDynamicSharedMemorySize, SM4);
  hipFuncSetAttribute((const void*)k_g6<8, 3, false>, hipFuncAttributeMaxDynamicSharedMemorySize, SM8);

  // 1) casts
  k_cast_all<<<dim3(14336), 256, 0, stream>>>(query, key, value, Wq, Wk, Wv, Wo,
                                              Xq, Xk, Xv, Wqb, Wkb, Wvb, Wob);

  // 2) merged Q/K/V projections: 3 slabs x (GM=64 x GN=4) = 768 wg, one dispatch
  k_g6<4, 1, false, true><<<768, 512, SM4, stream>>>(
      Xq, E_DIM, 0, Wqb, E_DIM, 0, Qb, E_DIM, 0, E_DIM, 1.0f, bq, nullptr, 64, 4,
      Xk, Xv, Wkb, Wvb, bk, bv, Kb, Vt);

  // 3) P = exp(Q K^T / 32): BM=BN=256, grid 8x8x4 = 256
  k_g6<8, 3, false><<<256, 512, SM8, stream>>>(
      Qb, E_DIM, (long)SEQ * E_DIM, Kb, E_DIM, (long)SEQ * E_DIM,
      SC, SEQ, (long)SEQ * SEQ, E_DIM, 0.03125f, nullptr, nullptr, 8, 8);

  // 4) ctx = (P @ V) / rowsum — rowsum via ones-MFMA, lane-local normalize
  //    grid 16x4x4 = 256
  k_g6<4, 1, true><<<256, 512, SM4, stream>>>(
      SC, SEQ, (long)SEQ * SEQ, Vt, SEQ, (long)E_DIM * SEQ,
      Ctx, E_DIM, (long)SEQ * E_DIM, SEQ, 1.0f, nullptr, nullptr, 16, 4);

  // 5) out = ctx Wo^T + bo + residual(query): grid 64x4 = 256, f32 out
  k_g6<4, 0, false><<<256, 512, SM4, stream>>>(
      Ctx, E_DIM, 0, Wob, E_DIM, 0, out, E_DIM, 0, E_DIM, 1.0f, bo, query, 64, 4);

  // 6) layernorm in-place
  k_layernorm<<<dim3(NTOK), 256, 0, stream>>>(out, gamma, beta);
}

// Round 10
// 230.719 us; speedup vs baseline: 1.1271x; 1.0070x over previous
//
#include <hip/hip_runtime.h>
#include <hip/hip_bf16.h>

typedef __bf16 bf16_t;
typedef __bf16 bf16x4 __attribute__((ext_vector_type(4)));
typedef __bf16 bf16x8 __attribute__((ext_vector_type(8)));
typedef float f32x4 __attribute__((ext_vector_type(4)));

#define E_DIM 1024
#define SEQ   2048
#define NBATCH 4

#define BARR()  asm volatile("s_barrier" ::: "memory")
#define LGKM0() asm volatile("s_waitcnt lgkmcnt(0)" ::: "memory")
#define VMC6()  asm volatile("s_waitcnt vmcnt(6)" ::: "memory")
#define VMC0()  asm volatile("s_waitcnt vmcnt(0)" ::: "memory")

// ---------------- all casts in one dispatch (plain row-major bf16) -------------
__global__ __launch_bounds__(256) void k_cast_all(
    const float* __restrict__ q, const float* __restrict__ k, const float* __restrict__ v,
    const float* __restrict__ wq, const float* __restrict__ wk,
    const float* __restrict__ wv, const float* __restrict__ wo,
    bf16_t* __restrict__ xq, bf16_t* __restrict__ xk, bf16_t* __restrict__ xv,
    bf16_t* __restrict__ wqb, bf16_t* __restrict__ wkb,
    bf16_t* __restrict__ wvb, bf16_t* __restrict__ wob) {
  const int b = blockIdx.x;
  const float* s; bf16_t* d; long base;
  if (b < 4096)        { s = q; d = xq; base = (long)b * 2048; }
  else if (b < 8192)   { s = k; d = xk; base = (long)(b - 4096) * 2048; }
  else if (b < 12288)  { s = v; d = xv; base = (long)(b - 8192) * 2048; }
  else {
    const int w = (b - 12288) >> 9, r = (b - 12288) & 511;
    s = (w == 0) ? wq : (w == 1) ? wk : (w == 2) ? wv : wo;
    d = (w == 0) ? wqb : (w == 1) ? wkb : (w == 2) ? wvb : wob;
    base = (long)r * 2048;
  }
  const long i = base + threadIdx.x * 8;
  const float4 a = *(const float4*)(s + i);
  const float4 c = *(const float4*)(s + i + 4);
  bf16x8 o;
  o[0] = (bf16_t)a.x; o[1] = (bf16_t)a.y; o[2] = (bf16_t)a.z; o[3] = (bf16_t)a.w;
  o[4] = (bf16_t)c.x; o[5] = (bf16_t)c.y; o[6] = (bf16_t)c.z; o[7] = (bf16_t)c.w;
  *(bf16x8*)(d + i) = o;
}

// =================================================================================
// 4-phase deep-pipelined GEMM, resized for 2 wg/CU.  C = scale*(A@B^T)+bias(...).
// A:[M][K] bf16 (lda), B:[N][K] bf16 (ldb), K-contiguous.
// Tile 128x128, BK=64, 256 thr = 4 waves (2x2), per-wave 64x64 via
// mfma_f32_16x16x32_bf16 (16x16 granules -> conflict-free XOR-8 reads, 0.5 rd/MFMA).
// LDS: 2 x (A 16KB + B 16KB) = 64KB  ->  TWO workgroups per CU (cross-wg TLP is
// the overlap donor; round-3 evidence it reaches the structural roofline).
// Per tile: ph0{ldA0,ldB0; stage Bh1(t+1)->buf^1}, ph1{ldB1},
// ph2{ldA1; stage Bh0(t+2)->cur}, ph3{stage A(t+2)->cur; mma; VMC6}.
// Ledger (8 GLL/tile): at ph3 wait, outstanding 14 -> retire tile t+1's 8, keep 6.
// OUTMODE 0:f32+bias+residual, 1:bf16+bias, 2:bf16 transposed Vt[b][col][s]+bias,
// 3: bf16 exp(v*scale).  RS: ones-MFMA rowsum (lane-local), scale rows by 1/rs.
// QKV3: 3 projection slabs of GM*GN wgs each in one dispatch; slab 2 transposed.
// =================================================================================
template <int OUTMODE, bool RS, bool QKV3 = false>
__global__ __launch_bounds__(256, 2) void k_g10(
    const bf16_t* __restrict__ A, int lda, long sA,
    const bf16_t* __restrict__ B, int ldb, long sB,
    void* __restrict__ Cv, int ldc, long sC,
    int K, float scale, const float* __restrict__ bias,
    const float* __restrict__ residual, int GM, int GN,
    const bf16_t* __restrict__ A1 = nullptr, const bf16_t* __restrict__ A2 = nullptr,
    const bf16_t* __restrict__ B1 = nullptr, const bf16_t* __restrict__ B2 = nullptr,
    const float* __restrict__ bias1 = nullptr, const float* __restrict__ bias2 = nullptr,
    void* __restrict__ Cv1 = nullptr, void* __restrict__ Cv2 = nullptr) {
  constexpr int ASZ   = 16384;          // A tile bytes (128 x 64 bf16)
  constexpr int BUFSZ = 32768;          // A + B per buffer
  extern __shared__ char smem[];

  const int tid  = threadIdx.x;
  const int lane = tid & 63;
  const int wid  = tid >> 6;
  const int wm   = wid >> 1;            // 0..1
  const int wn   = wid & 1;             // 0..1
  const int l15  = lane & 15;
  const int lq   = lane >> 4;           // k-chunk 0..3

  // T1: XCD swizzle (grids are multiples of 8)
  const int nwg  = gridDim.x;
  const int orig = blockIdx.x;
  const int wg0  = (orig & 7) * (nwg >> 3) + (orig >> 3);

  int pid = 0, wg = wg0;
  if constexpr (QKV3) { pid = wg0 / (GM * GN); wg = wg0 - pid * (GM * GN); }

  const int zz   = wg / (GM * GN);
  const int rm   = wg - zz * (GM * GN);
  const int bm   = rm / GN;
  const int bn   = rm - bm * GN;
  const int brow = bm * 128;
  const int bcol = bn * 128;

  const bf16_t* Ap = A;
  const bf16_t* Bp = B;
  const float*  biasp = bias;
  void* Cvp = Cv;
  bool tr = (OUTMODE == 2);
  if constexpr (QKV3) {
    if (pid == 1) { Ap = A1; Bp = B1; biasp = bias1; Cvp = Cv1; }
    else if (pid == 2) { Ap = A2; Bp = B2; biasp = bias2; Cvp = Cv2; tr = true; }
  }

  // staging source (inverse-swizzled col; row&7 == (tid>>3)&7 since bases %32==0)
  const int colk = ((tid & 7) ^ ((tid >> 3) & 7)) << 3;
  const bf16_t* Asrc = Ap + zz * sA + (long)(brow + (tid >> 3)) * lda + colk;
  const bf16_t* Bsrc = Bp + zz * sB + (long)(bcol + (tid >> 3)) * ldb + colk;
  const int ldsw = wid << 10;           // 4 waves x 1KB = one 4KB (32-row) unit
  const int NT = K >> 6;

#define GLL(gaddr, ldsoff)                                                       \
  __builtin_amdgcn_global_load_lds(                                             \
      (const __attribute__((address_space(1))) void*)(gaddr),                   \
      (__attribute__((address_space(3))) void*)(smem + (ldsoff)), 16, 0, 0)

  auto stA = [&](int tile, int buf) {   // full A tile: 4 x 4KB units (128 rows)
#pragma unroll
    for (int s = 0; s < 4; ++s)
      GLL(Asrc + (long)(s * 32) * lda + tile * 64, buf * BUFSZ + s * 4096 + ldsw);
  };
  auto stB = [&](int tile, int buf, int half) {  // B half: 64 rows = 2 units
#pragma unroll
    for (int s = 0; s < 2; ++s)
      GLL(Bsrc + (long)(half * 64 + s * 32) * ldb + tile * 64,
          buf * BUFSZ + ASZ + half * 8192 + s * 4096 + ldsw);
  };

  f32x4 acc[4][4];
#pragma unroll
  for (int m = 0; m < 4; ++m)
#pragma unroll
    for (int n = 0; n < 4; ++n) acc[m][n] = (f32x4){0.f, 0.f, 0.f, 0.f};
  f32x4 rs[4];
#pragma unroll
  for (int m = 0; m < 4; ++m) rs[m] = (f32x4){0.f, 0.f, 0.f, 0.f};
  bf16x8 vones;
#pragma unroll
  for (int i = 0; i < 8; ++i) vones[i] = (bf16_t)1.0f;

  // ds_read fragment loaders (swizzled, 16-row pattern: conflict-free)
  auto ldA = [&](bf16x8 (&a)[2][2], int cur, int mq) {
#pragma unroll
    for (int i = 0; i < 2; ++i) {
      const int row = wm * 64 + (mq * 2 + i) * 16 + l15;
#pragma unroll
      for (int kk = 0; kk < 2; ++kk) {
        const int byt = cur * BUFSZ + row * 128 + ((kk * 64 + lq * 16) ^ ((row & 7) << 4));
        a[i][kk] = *(const bf16x8*)(smem + byt);
      }
    }
  };
  auto ldB = [&](bf16x8 (&b)[2][2], int cur, int nq) {
#pragma unroll
    for (int n2 = 0; n2 < 2; ++n2) {
      const int row = wn * 64 + (nq * 2 + n2) * 16 + l15;
#pragma unroll
      for (int kk = 0; kk < 2; ++kk) {
        const int byt = cur * BUFSZ + ASZ + row * 128 + ((kk * 64 + lq * 16) ^ ((row & 7) << 4));
        b[n2][kk] = *(const bf16x8*)(smem + byt);
      }
    }
  };
  auto mmaq = [&](bf16x8 (&a)[2][2], bf16x8 (&b)[2][2], int mq, int nq) {
    __builtin_amdgcn_s_setprio(1);
#pragma unroll
    for (int kk = 0; kk < 2; ++kk)
#pragma unroll
      for (int i = 0; i < 2; ++i)
#pragma unroll
        for (int n2 = 0; n2 < 2; ++n2)
          acc[mq * 2 + i][nq * 2 + n2] = __builtin_amdgcn_mfma_f32_16x16x32_bf16(
              a[i][kk], b[n2][kk], acc[mq * 2 + i][nq * 2 + n2], 0, 0, 0);
    __builtin_amdgcn_s_setprio(0);
  };
  auto mmars = [&](bf16x8 (&a)[2][2], int mq) {
#pragma unroll
    for (int kk = 0; kk < 2; ++kk)
#pragma unroll
      for (int i = 0; i < 2; ++i)
        rs[mq * 2 + i] = __builtin_amdgcn_mfma_f32_16x16x32_bf16(
            a[i][kk], vones, rs[mq * 2 + i], 0, 0, 0);
  };

  // ---------------- prologue: t0 full (8) + t1 {Bh0 (2), A (4)}; VMC6 -----------
  {
    const int t1c = 1 < NT ? 1 : 0;
    stB(0, 0, 0); stB(0, 0, 1); stA(0, 0);
    stB(t1c, 1, 0); stA(t1c, 1);
    VMC6();   // 14 outstanding -> retire tile0's 8, keep t1's 6
    BARR();
  }

  bf16x8 a0[2][2], a1[2][2], b0[2][2], b1[2][2];
  auto tile = [&](int t, int cur) {
    const int t1 = t + 1 < NT ? t + 1 : NT - 1;
    const int t2 = t + 2 < NT ? t + 2 : NT - 1;
    // ph0: reads a0,b0 ; stage Bh1(t+1)->buf^1 (readers finished last tile)
    ldA(a0, cur, 0); ldB(b0, cur, 0);
    stB(t1, cur ^ 1, 1);
    BARR(); LGKM0();
    mmaq(a0, b0, 0, 0);
    BARR();
    // ph1: reads b1
    ldB(b1, cur, 1);
    BARR(); LGKM0();
    mmaq(a0, b1, 0, 1);
    if constexpr (RS) mmars(a0, 0);
    BARR();
    // ph2: reads a1 ; stage Bh0(t+2)->cur (Bh0 last read ph0, barrier passed)
    ldA(a1, cur, 1);
    stB(t2, cur, 0);
    BARR(); LGKM0();
    mmaq(a1, b1, 1, 1);
    BARR();
    // ph3: stage A(t+2)->cur (A last read ph2, barrier passed); counted vmcnt
    stA(t2, cur);
    BARR();
    mmaq(a1, b0, 1, 0);
    if constexpr (RS) mmars(a1, 1);
    VMC6();   // retire tile t+1's 8 loads; keep tile t+2's 6 in flight
    BARR();
  };

  for (int t = 0; t < NT; t += 2) {
    tile(t, 0);
    tile(t + 1, 1);
  }
  VMC0();

  // ---------------- epilogue (C/D 16x16: col=lane&15, row=(lane>>4)*4+j) --------
  const int colb = bcol + wn * 64 + l15;
  const int rowb = brow + wm * 64 + lq * 4;
#pragma unroll
  for (int m = 0; m < 4; ++m) {
    float inv[4];
    if constexpr (RS) {
#pragma unroll
      for (int j = 0; j < 4; ++j) inv[j] = 1.0f / rs[m][j];
    }
#pragma unroll
    for (int n = 0; n < 4; ++n) {
      const int colg = colb + n * 16;
      float bval = 0.0f;
      if constexpr (OUTMODE != 3) bval = biasp ? biasp[colg] : 0.0f;
      if ((OUTMODE == 2) || (QKV3 && tr)) {
        const int r0 = rowb + m * 16;
        bf16x4 pk;
#pragma unroll
        for (int j = 0; j < 4; ++j) pk[j] = (bf16_t)(acc[m][n][j] * scale + bval);
        const long bb = (long)(r0 >> 11);
        const int ss = r0 & (SEQ - 1);
        *(bf16x4*)((bf16_t*)Cvp + bb * ((long)E_DIM * SEQ) + (long)colg * SEQ + ss) = pk;
      } else {
#pragma unroll
        for (int j = 0; j < 4; ++j) {
          const int r = rowb + m * 16 + j;
          float v;
          if constexpr (OUTMODE == 3) v = __expf(acc[m][n][j] * scale);
          else v = acc[m][n][j] * scale + bval;
          if constexpr (RS) v *= inv[j];
          if (OUTMODE == 0 && residual) v += residual[(long)r * ldc + colg];
          const long idx = (long)zz * sC + (long)r * ldc + colg;
          if constexpr (OUTMODE == 0) ((float*)Cvp)[idx] = v;
          else ((bf16_t*)Cvp)[idx] = (bf16_t)v;
        }
      }
    }
  }
#undef GLL
}

// ---------------- layernorm in-place on rows of 1024 f32 ----------------
__global__ __launch_bounds__(256) void k_layernorm(float* __restrict__ out,
                                                   const float* __restrict__ gamma,
                                                   const float* __restrict__ beta) {
  const long row = blockIdx.x;
  float* rp = out + row * 1024;
  const int t = threadIdx.x;
  const float4 v = *(const float4*)(rp + t * 4);
  float s = v.x + v.y + v.z + v.w;
#pragma unroll
  for (int o = 32; o; o >>= 1) s += __shfl_xor(s, o);
  __shared__ float red1[4], red2[4];
  const int lane = t & 63, w = t >> 6;
  if (lane == 0) red1[w] = s;
  __syncthreads();
  const float mu = (red1[0] + red1[1] + red1[2] + red1[3]) * (1.0f / 1024.0f);
  const float d0 = v.x - mu, d1 = v.y - mu, d2 = v.z - mu, d3 = v.w - mu;
  float ss = d0 * d0 + d1 * d1 + d2 * d2 + d3 * d3;
#pragma unroll
  for (int o = 32; o; o >>= 1) ss += __shfl_xor(ss, o);
  if (lane == 0) red2[w] = ss;
  __syncthreads();
  const float var = (red2[0] + red2[1] + red2[2] + red2[3]) * (1.0f / 1024.0f);
  const float rsq = rsqrtf(var + 1e-6f);
  const float4 g = *(const float4*)(gamma + t * 4);
  const float4 b = *(const float4*)(beta + t * 4);
  float4 o;
  o.x = d0 * rsq * g.x + b.x;
  o.y = d1 * rsq * g.y + b.y;
  o.z = d2 * rsq * g.z + b.z;
  o.w = d3 * rsq * g.w + b.w;
  *(float4*)(rp + t * 4) = o;
}

extern "C" void kernel_launch(void* const* d_in, const int* in_sizes, int n_in,
                              void* d_out, int out_size, void* d_ws, size_t ws_size,
                              hipStream_t stream) {
  const float* query = (const float*)d_in[0];
  const float* key   = (const float*)d_in[1];
  const float* value = (const float*)d_in[2];
  const float* Wq = (const float*)d_in[3];
  const float* bq = (const float*)d_in[4];
  const float* Wk = (const float*)d_in[5];
  const float* bk = (const float*)d_in[6];
  const float* Wv = (const float*)d_in[7];
  const float* bv = (const float*)d_in[8];
  const float* Wo = (const float*)d_in[9];
  const float* bo = (const float*)d_in[10];
  const float* gamma = (const float*)d_in[11];
  const float* beta  = (const float*)d_in[12];
  float* out = (float*)d_out;

  char* ws = (char*)d_ws;
  const size_t XSZ = (size_t)NBATCH * SEQ * E_DIM * 2;  // 16 MiB
  const size_t WSZ = (size_t)E_DIM * E_DIM * 2;         // 2 MiB
  const size_t B2  = 3 * XSZ;                           // 48 MiB boundary

  bf16_t* Xq  = (bf16_t*)(ws + 0);
  bf16_t* Xk  = (bf16_t*)(ws + XSZ);
  bf16_t* Xv  = (bf16_t*)(ws + 2 * XSZ);
  bf16_t* SC  = (bf16_t*)(ws + 0);   // exp-scores overlay dead X buffers (33.5MB<48)
  bf16_t* Wqb = (bf16_t*)(ws + B2);
  bf16_t* Wkb = (bf16_t*)(ws + B2 + WSZ);
  bf16_t* Wvb = (bf16_t*)(ws + B2 + 2 * WSZ);
  bf16_t* Wob = (bf16_t*)(ws + B2 + 3 * WSZ);
  bf16_t* Qb  = (bf16_t*)(ws + B2 + 4 * WSZ);
  bf16_t* Kb  = (bf16_t*)(ws + B2 + 4 * WSZ + XSZ);
  bf16_t* Vt  = (bf16_t*)(ws + B2 + 4 * WSZ + 2 * XSZ);
  bf16_t* Ctx = (bf16_t*)(ws + B2 + 4 * WSZ + 3 * XSZ);

  const int NTOK = NBATCH * SEQ;  // 8192
  const int SMB = 65536;          // 2 x 32KB -> 2 wg/CU

  hipFuncSetAttribute((const void*)k_g10<1, false, true>, hipFuncAttributeMaxDynamicSharedMemorySize, SMB);
  hipFuncSetAttribute((const void*)k_g10<3, false>, hipFuncAttributeMaxDynamicSharedMemorySize, SMB);
  hipFuncSetAttribute((const void*)k_g10<1, true>,  hipFuncAttributeMaxDynamicSharedMemorySize, SMB);
  hipFuncSetAttribute((const void*)k_g10<0, false>, hipFuncAttributeMaxDynamicSharedMemorySize, SMB);

  // 1) casts
  k_cast_all<<<dim3(14336), 256, 0, stream>>>(query, key, value, Wq, Wk, Wv, Wo,
                                              Xq, Xk, Xv, Wqb, Wkb, Wvb, Wob);

  // 2) merged Q/K/V projections: 3 slabs x (GM=64 x GN=8) = 1536 wg
  k_g10<1, false, true><<<1536, 256, SMB, stream>>>(
      Xq, E_DIM, 0, Wqb, E_DIM, 0, Qb, E_DIM, 0, E_DIM, 1.0f, bq, nullptr, 64, 8,
      Xk, Xv, Wkb, Wvb, bk, bv, Kb, Vt);

  // 3) P = exp(Q K^T / 32): grid 16x16x4 = 1024
  k_g10<3, false><<<1024, 256, SMB, stream>>>(
      Qb, E_DIM, (long)SEQ * E_DIM, Kb, E_DIM, (long)SEQ * E_DIM,
      SC, SEQ, (long)SEQ * SEQ, E_DIM, 0.03125f, nullptr, nullptr, 16, 16);

  // 4) ctx = (P @ V) / rowsum — ones-MFMA rowsum, lane-local normalize
  //    grid 16x8x4 = 512
  k_g10<1, true><<<512, 256, SMB, stream>>>(
      SC, SEQ, (long)SEQ * SEQ, Vt, SEQ, (long)E_DIM * SEQ,
      Ctx, E_DIM, (long)SEQ * E_DIM, SEQ, 1.0f, nullptr, nullptr, 16, 8);

  // 5) out = ctx Wo^T + bo + residual(query): grid 64x8 = 512, f32 out
  k_g10<0, false><<<512, 256, SMB, stream>>>(
      Ctx, E_DIM, 0, Wob, E_DIM, 0, out, E_DIM, 0, E_DIM, 1.0f, bo, query, 64, 8);

  // 6) layernorm in-place
  k_layernorm<<<dim3(NTOK), 256, 0, stream>>>(out, gamma, beta);
}